// Round 1
// baseline (398.616 us; speedup 1.0000x reference)
//
#include <hip/hip_runtime.h>
#include <hip/hip_bf16.h>

#define N_NODES_C 100000
#define D_IN_C 16
#define D_OUT_C 32

// Kernel 1: h = relu(x@w1+b1)@w2+b2, plus zero-init of summed/cnt.
__global__ __launch_bounds__(256) void mlp_kernel(
    const float* __restrict__ x,
    const float* __restrict__ w1, const float* __restrict__ b1,
    const float* __restrict__ w2, const float* __restrict__ b2,
    float* __restrict__ h, float* __restrict__ summed, int* __restrict__ cnt,
    int n_nodes) {
  __shared__ float sw1[256];
  __shared__ float sw2[256];
  __shared__ float sb1[16];
  __shared__ float sb2[16];
  int t = threadIdx.x;
  sw1[t] = w1[t];
  sw2[t] = w2[t];
  if (t < 16) { sb1[t] = b1[t]; sb2[t] = b2[t]; }
  __syncthreads();

  int n = blockIdx.x * blockDim.x + t;
  if (n >= n_nodes) return;

  float xi[16];
  const float4* xr = (const float4*)(x + (size_t)n * 16);
  float4 v0 = xr[0], v1 = xr[1], v2 = xr[2], v3 = xr[3];
  xi[0]=v0.x; xi[1]=v0.y; xi[2]=v0.z; xi[3]=v0.w;
  xi[4]=v1.x; xi[5]=v1.y; xi[6]=v1.z; xi[7]=v1.w;
  xi[8]=v2.x; xi[9]=v2.y; xi[10]=v2.z; xi[11]=v2.w;
  xi[12]=v3.x; xi[13]=v3.y; xi[14]=v3.z; xi[15]=v3.w;

  float t1[16];
#pragma unroll
  for (int j = 0; j < 16; ++j) {
    float acc = sb1[j];
#pragma unroll
    for (int k = 0; k < 16; ++k) acc += xi[k] * sw1[k * 16 + j];
    t1[j] = fmaxf(acc, 0.0f);
  }
  float hh[16];
#pragma unroll
  for (int j = 0; j < 16; ++j) {
    float acc = sb2[j];
#pragma unroll
    for (int k = 0; k < 16; ++k) acc += t1[k] * sw2[k * 16 + j];
    hh[j] = acc;
  }

  float4* hw = (float4*)(h + (size_t)n * 16);
  hw[0] = make_float4(hh[0], hh[1], hh[2], hh[3]);
  hw[1] = make_float4(hh[4], hh[5], hh[6], hh[7]);
  hw[2] = make_float4(hh[8], hh[9], hh[10], hh[11]);
  hw[3] = make_float4(hh[12], hh[13], hh[14], hh[15]);

  // zero-init accumulators (ws is poisoned before every launch)
  float4* sz = (float4*)(summed + (size_t)n * 16);
  float4 z = make_float4(0.f, 0.f, 0.f, 0.f);
  sz[0] = z; sz[1] = z; sz[2] = z; sz[3] = z;
  cnt[n] = 0;
}

// Kernel 2: scatter-add. 16 threads per edge.
__global__ __launch_bounds__(256) void scatter_kernel(
    const int* __restrict__ src, const int* __restrict__ dst,
    const float* __restrict__ h, float* __restrict__ summed,
    int* __restrict__ cnt, long long n_edges) {
  long long tid = (long long)blockIdx.x * blockDim.x + threadIdx.x;
  long long e = tid >> 4;
  int k = (int)(tid & 15);
  if (e >= n_edges) return;
  int s = src[e];
  int d = dst[e];
  float val = h[(size_t)s * 16 + k];
  atomicAdd(&summed[(size_t)d * 16 + k], val);
  if (k == 0) atomicAdd(&cnt[d], 1);
}

// Kernel 3: out = (summed/max(cnt,1)) @ wl + bl + h @ wr
__global__ __launch_bounds__(256) void out_kernel(
    const float* __restrict__ h, const float* __restrict__ summed,
    const int* __restrict__ cnt,
    const float* __restrict__ wl, const float* __restrict__ bl,
    const float* __restrict__ wr, float* __restrict__ out, int n_nodes) {
  __shared__ float swl[512];
  __shared__ float swr[512];
  __shared__ float sbl[32];
  int t = threadIdx.x;
  for (int i = t; i < 512; i += 256) { swl[i] = wl[i]; swr[i] = wr[i]; }
  if (t < 32) sbl[t] = bl[t];
  __syncthreads();

  int gid = blockIdx.x * 256 + t;
  int n = gid >> 5;
  int j = gid & 31;
  if (n >= n_nodes) return;

  float inv = 1.0f / fmaxf((float)cnt[n], 1.0f);
  const float* hr = h + (size_t)n * 16;
  const float* sr = summed + (size_t)n * 16;
  float acc = sbl[j];
#pragma unroll
  for (int k = 0; k < 16; ++k) {
    acc += sr[k] * inv * swl[k * 32 + j] + hr[k] * swr[k * 32 + j];
  }
  out[(size_t)n * 32 + j] = acc;
}

extern "C" void kernel_launch(void* const* d_in, const int* in_sizes, int n_in,
                              void* d_out, int out_size, void* d_ws, size_t ws_size,
                              hipStream_t stream) {
  const float* x  = (const float*)d_in[0];
  const int* eidx = (const int*)d_in[1];
  const float* w1 = (const float*)d_in[2];
  const float* b1 = (const float*)d_in[3];
  const float* w2 = (const float*)d_in[4];
  const float* b2 = (const float*)d_in[5];
  const float* wl = (const float*)d_in[6];
  const float* bl = (const float*)d_in[7];
  const float* wr = (const float*)d_in[8];
  float* out = (float*)d_out;

  const int n_nodes = in_sizes[0] / D_IN_C;           // 100000
  const long long n_edges = (long long)in_sizes[1] / 2; // 3200000
  const int* src = eidx;
  const int* dst = eidx + n_edges;

  float* h      = (float*)d_ws;                        // N*16 f32
  float* summed = h + (size_t)n_nodes * 16;            // N*16 f32
  int*   cnt    = (int*)(summed + (size_t)n_nodes * 16); // N int

  // Kernel 1: MLP + zero init
  {
    int blocks = (n_nodes + 255) / 256;
    mlp_kernel<<<blocks, 256, 0, stream>>>(x, w1, b1, w2, b2, h, summed, cnt, n_nodes);
  }
  // Kernel 2: scatter
  {
    long long total = n_edges * 16;
    int blocks = (int)((total + 255) / 256);
    scatter_kernel<<<blocks, 256, 0, stream>>>(src, dst, h, summed, cnt, n_edges);
  }
  // Kernel 3: epilogue
  {
    long long total = (long long)n_nodes * 32;
    int blocks = (int)((total + 255) / 256);
    out_kernel<<<blocks, 256, 0, stream>>>(h, summed, cnt, wl, bl, wr, out, n_nodes);
  }
}